// Round 1
// baseline (1232.344 us; speedup 1.0000x reference)
//
#include <hip/hip_runtime.h>

#define NSUP 4096
#define NTOT 8192
#define DIN  512
#define DEMB 256
#define NCLS 64
#define KSPLIT 8

typedef __attribute__((ext_vector_type(8))) short bf16x8;
typedef __attribute__((ext_vector_type(4))) float f32x4;
typedef __attribute__((ext_vector_type(4))) unsigned int u32x4;

__device__ inline unsigned short f2bf(float x) {
  unsigned int u = __builtin_bit_cast(unsigned int, x);
  u += 0x7FFFu + ((u >> 16) & 1u);   // RNE
  return (unsigned short)(u >> 16);
}
__device__ inline float bf2f(unsigned short h) {
  unsigned int u = ((unsigned int)h) << 16;
  return __builtin_bit_cast(float, u);
}

// ---------- 1) emb = [support;query] @ W (fp32), split into bf16 hi/lo ----------
__global__ __launch_bounds__(256) void emb_kernel(
    const float* __restrict__ support, const float* __restrict__ query,
    const float* __restrict__ W, unsigned short* __restrict__ ehi,
    unsigned short* __restrict__ elo) {
  int c = threadIdx.x;              // 0..255 = embedding col
  int r0 = blockIdx.x * 8;          // 8 rows per block
  const float* X = (r0 < NSUP) ? (support + (size_t)r0 * DIN)
                               : (query + (size_t)(r0 - NSUP) * DIN);
  float acc[8] = {0.f,0.f,0.f,0.f,0.f,0.f,0.f,0.f};
  #pragma unroll 4
  for (int k = 0; k < DIN; k++) {
    float wv = W[k * DEMB + c];
    #pragma unroll
    for (int r = 0; r < 8; r++) acc[r] += X[r * DIN + k] * wv;
  }
  #pragma unroll
  for (int r = 0; r < 8; r++) {
    float e = acc[r];
    unsigned short h = f2bf(e);
    float lo = e - bf2f(h);
    size_t o = (size_t)(r0 + r) * DEMB + c;
    ehi[o] = h;
    elo[o] = f2bf(lo);
  }
}

// ---------- 2) similarity (split-bf16 MFMA) -> threshold -> bitpacked adjacency ----------
__global__ __launch_bounds__(256) void sim_kernel(
    const unsigned short* __restrict__ ehi, const unsigned short* __restrict__ elo,
    unsigned short* __restrict__ Abits) {
  int lane = threadIdx.x & 63;
  int w = threadIdx.x >> 6;         // 4 waves, 2x2
  int wm = w >> 1, wn = w & 1;
  int br = blockIdx.y * 128 + wm * 64;
  int bc = blockIdx.x * 128 + wn * 64;
  int l15 = lane & 15, lg = lane >> 4;

  f32x4 acc[4][4] = {};
  for (int kb = 0; kb < DEMB; kb += 32) {
    int koff = kb + lg * 8;
    bf16x8 bh[4], bl[4];
    #pragma unroll
    for (int fn = 0; fn < 4; fn++) {
      size_t o = (size_t)(bc + fn * 16 + l15) * DEMB + koff;
      bh[fn] = *reinterpret_cast<const bf16x8*>(ehi + o);
      bl[fn] = *reinterpret_cast<const bf16x8*>(elo + o);
    }
    #pragma unroll
    for (int fm = 0; fm < 4; fm++) {
      size_t o = (size_t)(br + fm * 16 + l15) * DEMB + koff;
      bf16x8 ah = *reinterpret_cast<const bf16x8*>(ehi + o);
      bf16x8 al = *reinterpret_cast<const bf16x8*>(elo + o);
      #pragma unroll
      for (int fn = 0; fn < 4; fn++) {
        acc[fm][fn] = __builtin_amdgcn_mfma_f32_16x16x32_bf16(ah, bh[fn], acc[fm][fn], 0, 0, 0);
        acc[fm][fn] = __builtin_amdgcn_mfma_f32_16x16x32_bf16(ah, bl[fn], acc[fm][fn], 0, 0, 0);
        acc[fm][fn] = __builtin_amdgcn_mfma_f32_16x16x32_bf16(al, bh[fn], acc[fm][fn], 0, 0, 0);
      }
    }
  }
  // threshold + ballot-pack: C/D layout col=l&15, row=(l>>4)*4+reg
  #pragma unroll
  for (int fm = 0; fm < 4; fm++) {
    #pragma unroll
    for (int r = 0; r < 4; r++) {
      int grow = br + fm * 16 + lg * 4 + r;
      #pragma unroll
      for (int fn = 0; fn < 4; fn++) {
        unsigned long long bal = __ballot(acc[fm][fn][r] > 0.5f);
        if (l15 == 0) {
          Abits[(size_t)grow * (NTOT / 16) + ((bc + fn * 16) >> 4)] =
              (unsigned short)(bal >> (lg * 16));
        }
      }
    }
  }
}

// ---------- 3) degree = popcount of adjacency rows ----------
__global__ __launch_bounds__(256) void degree_kernel(
    const unsigned long long* __restrict__ A64, float* __restrict__ degree) {
  int row = blockIdx.x * 4 + (threadIdx.x >> 6);
  int lane = threadIdx.x & 63;
  const unsigned long long* p = A64 + (size_t)row * (NTOT / 64);
  int cnt = __popcll(p[lane]) + __popcll(p[lane + 64]);
  #pragma unroll
  for (int off = 32; off > 0; off >>= 1) cnt += __shfl_down(cnt, off);
  if (lane == 0) degree[row] = (float)cnt;
}

// ---------- 4) label init: support one-hot, query zero ----------
__global__ __launch_bounds__(256) void init_labels(
    const int* __restrict__ slab, float* __restrict__ labels,
    unsigned short* __restrict__ Lt) {
  int idx = blockIdx.x * 256 + threadIdx.x;
  int i = idx >> 6, c = idx & 63;
  float v = 0.f;
  if (i < NSUP && slab[i] == c) v = 1.f;
  labels[idx] = v;
  Lt[(size_t)c * NTOT + i] = f2bf(v);
}

// ---------- 5) prop GEMM: Cpart[p] = A[:, kchunk] @ L[kchunk, :]  (bitmask-unpacked bf16 MFMA) ----------
__global__ __launch_bounds__(256) void prop_gemm(
    const unsigned char* __restrict__ Abytes, const unsigned short* __restrict__ Lt,
    float* __restrict__ Cpart) {
  int lane = threadIdx.x & 63;
  int w = threadIdx.x >> 6;                 // 4 waves, 16 rows each
  int l15 = lane & 15, lg = lane >> 4;
  int rowbase = blockIdx.x * 64 + w * 16;
  int kc = blockIdx.y * (NTOT / KSPLIT);    // 1024-wide K chunk
  int row = rowbase + l15;
  const unsigned char* ap = Abytes + (size_t)row * (NTOT / 8) + (kc >> 3) + lg;
  f32x4 acc[4] = {};
  const int NSTEP = (NTOT / KSPLIT) / 32;   // 32
  for (int s = 0; s < NSTEP; s++) {
    unsigned int bb = ap[(size_t)s * 4];    // 8 K-bits for this lane's row
    u32x4 uu;
    uu.x = ((bb & 1u)   ? 0x3F80u : 0u) | ((bb & 2u)   ? 0x3F800000u : 0u);
    uu.y = ((bb & 4u)   ? 0x3F80u : 0u) | ((bb & 8u)   ? 0x3F800000u : 0u);
    uu.z = ((bb & 16u)  ? 0x3F80u : 0u) | ((bb & 32u)  ? 0x3F800000u : 0u);
    uu.w = ((bb & 64u)  ? 0x3F80u : 0u) | ((bb & 128u) ? 0x3F800000u : 0u);
    bf16x8 a = __builtin_bit_cast(bf16x8, uu);
    int koff = kc + s * 32 + lg * 8;
    #pragma unroll
    for (int fn = 0; fn < 4; fn++) {
      bf16x8 b = *reinterpret_cast<const bf16x8*>(Lt + (size_t)(fn * 16 + l15) * NTOT + koff);
      acc[fn] = __builtin_amdgcn_mfma_f32_16x16x32_bf16(a, b, acc[fn], 0, 0, 0);
    }
  }
  #pragma unroll
  for (int fn = 0; fn < 4; fn++) {
    #pragma unroll
    for (int r = 0; r < 4; r++) {
      int grow = rowbase + lg * 4 + r;
      int gcol = fn * 16 + l15;
      Cpart[((size_t)blockIdx.y * NTOT + grow) * NCLS + gcol] = acc[fn][r];
    }
  }
}

// ---------- 6) prop epilogue: reduce K-splits, 0.5*old + 0.5*sum/deg, refresh Lt ----------
__global__ __launch_bounds__(256) void prop_epilogue(
    const float* __restrict__ Cpart, const float* __restrict__ degree,
    float* __restrict__ labels, unsigned short* __restrict__ Lt,
    float* __restrict__ outq, int last) {
  int idx = blockIdx.x * 256 + threadIdx.x;
  int i = idx >> 6, c = idx & 63;
  float s = 0.f;
  #pragma unroll
  for (int p = 0; p < KSPLIT; p++) s += Cpart[(size_t)p * NTOT * NCLS + idx];
  float dg = degree[i];
  dg = (dg == 0.f) ? 1.f : dg;
  float v = 0.5f * labels[idx] + 0.5f * (s / dg);
  labels[idx] = v;
  Lt[(size_t)c * NTOT + i] = f2bf(v);
  if (last && i >= NSUP) outq[(size_t)(i - NSUP) * NCLS + c] = v;
}

extern "C" void kernel_launch(void* const* d_in, const int* in_sizes, int n_in,
                              void* d_out, int out_size, void* d_ws, size_t ws_size,
                              hipStream_t stream) {
  const float* support = (const float*)d_in[0];
  const float* query   = (const float*)d_in[1];
  const float* W       = (const float*)d_in[2];
  const int*   slab    = (const int*)d_in[3];
  float* out = (float*)d_out;
  char* ws = (char*)d_ws;
  const size_t MB = (size_t)1 << 20;
  unsigned char*  Abits  = (unsigned char*)(ws);            // 8 MB  bitpacked adjacency
  unsigned short* ehi    = (unsigned short*)(ws + 8 * MB);  // 4 MB  emb hi (bf16)
  unsigned short* elo    = (unsigned short*)(ws + 12 * MB); // 4 MB  emb lo (bf16)
  float*          labels = (float*)(ws + 16 * MB);          // 2 MB  labels fp32 [8192][64]
  unsigned short* Lt     = (unsigned short*)(ws + 18 * MB); // 1 MB  labels bf16 transposed [64][8192]
  float*          degree = (float*)(ws + 19 * MB);          // 32 KB
  float*          Cpart  = (float*)(ws + 20 * MB);          // 16 MB K-split partials

  emb_kernel<<<NTOT / 8, 256, 0, stream>>>(support, query, W, ehi, elo);
  sim_kernel<<<dim3(64, 64), 256, 0, stream>>>(ehi, elo, (unsigned short*)Abits);
  degree_kernel<<<NTOT / 4, 256, 0, stream>>>((const unsigned long long*)Abits, degree);
  init_labels<<<NTOT * NCLS / 256, 256, 0, stream>>>(slab, labels, Lt);
  for (int t = 0; t < 10; t++) {
    prop_gemm<<<dim3(NTOT / 64, KSPLIT), 256, 0, stream>>>(Abits, Lt, Cpart);
    prop_epilogue<<<NTOT * NCLS / 256, 256, 0, stream>>>(Cpart, degree, labels, Lt, out, (t == 9) ? 1 : 0);
  }
}

// Round 3
// 955.256 us; speedup vs baseline: 1.2901x; 1.2901x over previous
//
#include <hip/hip_runtime.h>

#define NSUP 4096
#define NTOT 8192
#define DIN  512
#define DEMB 256
#define NCLS 64

typedef __attribute__((ext_vector_type(8))) short bf16x8;
typedef __attribute__((ext_vector_type(4))) float f32x4;
typedef __attribute__((ext_vector_type(4))) unsigned int u32x4;

__device__ inline unsigned short f2bf(float x) {
  unsigned int u = __builtin_bit_cast(unsigned int, x);
  u += 0x7FFFu + ((u >> 16) & 1u);   // RNE
  return (unsigned short)(u >> 16);
}
__device__ inline float bf2f(unsigned short h) {
  unsigned int u = ((unsigned int)h) << 16;
  return __builtin_bit_cast(float, u);
}

// ---------- 1) emb = [support;query] @ W (fp32), split into bf16 hi/lo ----------
__global__ __launch_bounds__(256) void emb_kernel(
    const float* __restrict__ support, const float* __restrict__ query,
    const float* __restrict__ W, unsigned short* __restrict__ ehi,
    unsigned short* __restrict__ elo) {
  int c = threadIdx.x;              // 0..255 = embedding col
  int r0 = blockIdx.x * 8;          // 8 rows per block
  const float* X = (r0 < NSUP) ? (support + (size_t)r0 * DIN)
                               : (query + (size_t)(r0 - NSUP) * DIN);
  float acc[8] = {0.f,0.f,0.f,0.f,0.f,0.f,0.f,0.f};
  #pragma unroll 4
  for (int k = 0; k < DIN; k++) {
    float wv = W[k * DEMB + c];
    #pragma unroll
    for (int r = 0; r < 8; r++) acc[r] += X[r * DIN + k] * wv;
  }
  #pragma unroll
  for (int r = 0; r < 8; r++) {
    float e = acc[r];
    unsigned short h = f2bf(e);
    float lo = e - bf2f(h);
    size_t o = (size_t)(r0 + r) * DEMB + c;
    ehi[o] = h;
    elo[o] = f2bf(lo);
  }
}

// ---------- 2) similarity (split-bf16 MFMA), upper-triangular blocks only ----------
__global__ __launch_bounds__(256) void sim_kernel(
    const unsigned short* __restrict__ ehi, const unsigned short* __restrict__ elo,
    unsigned short* __restrict__ Abits) {
  if (blockIdx.x < blockIdx.y) return;     // A symmetric: mirror fills the rest
  int lane = threadIdx.x & 63;
  int w = threadIdx.x >> 6;         // 4 waves, 2x2
  int wm = w >> 1, wn = w & 1;
  int br = blockIdx.y * 128 + wm * 64;
  int bc = blockIdx.x * 128 + wn * 64;
  int l15 = lane & 15, lg = lane >> 4;

  f32x4 acc[4][4] = {};
  for (int kb = 0; kb < DEMB; kb += 32) {
    int koff = kb + lg * 8;
    bf16x8 bh[4], bl[4];
    #pragma unroll
    for (int fn = 0; fn < 4; fn++) {
      size_t o = (size_t)(bc + fn * 16 + l15) * DEMB + koff;
      bh[fn] = *reinterpret_cast<const bf16x8*>(ehi + o);
      bl[fn] = *reinterpret_cast<const bf16x8*>(elo + o);
    }
    #pragma unroll
    for (int fm = 0; fm < 4; fm++) {
      size_t o = (size_t)(br + fm * 16 + l15) * DEMB + koff;
      bf16x8 ah = *reinterpret_cast<const bf16x8*>(ehi + o);
      bf16x8 al = *reinterpret_cast<const bf16x8*>(elo + o);
      #pragma unroll
      for (int fn = 0; fn < 4; fn++) {
        acc[fm][fn] = __builtin_amdgcn_mfma_f32_16x16x32_bf16(ah, bh[fn], acc[fm][fn], 0, 0, 0);
        acc[fm][fn] = __builtin_amdgcn_mfma_f32_16x16x32_bf16(ah, bl[fn], acc[fm][fn], 0, 0, 0);
        acc[fm][fn] = __builtin_amdgcn_mfma_f32_16x16x32_bf16(al, bh[fn], acc[fm][fn], 0, 0, 0);
      }
    }
  }
  // threshold + ballot-pack: C/D layout col=l&15, row=(l>>4)*4+reg
  #pragma unroll
  for (int fm = 0; fm < 4; fm++) {
    #pragma unroll
    for (int r = 0; r < 4; r++) {
      int grow = br + fm * 16 + lg * 4 + r;
      #pragma unroll
      for (int fn = 0; fn < 4; fn++) {
        unsigned long long bal = __ballot(acc[fm][fn][r] > 0.5f);
        if (l15 == 0) {
          Abits[(size_t)grow * (NTOT / 16) + ((bc + fn * 16) >> 4)] =
              (unsigned short)(bal >> (lg * 16));
        }
      }
    }
  }
}

// ---------- 2b) mirror: fill strictly-lower 16x16 bit-tiles by bit-transpose ----------
__global__ __launch_bounds__(256) void mirror_kernel(unsigned short* __restrict__ A16) {
  int tr = blockIdx.x;                       // source tile row 0..511
  for (int tc = threadIdx.x; tc < NTOT / 16; tc += 256) {
    if ((tc >> 3) <= (tr >> 3)) continue;    // only tiles in strictly-upper 128-blocks
    unsigned int m[16], t;
    #pragma unroll
    for (int r = 0; r < 16; r++) m[r] = A16[(size_t)(tr * 16 + r) * (NTOT / 16) + tc];
    #pragma unroll
    for (int i = 0; i < 8; i++) { t = ((m[i] >> 8) ^ m[i + 8]) & 0x00FFu; m[i + 8] ^= t; m[i] ^= t << 8; }
    #pragma unroll
    for (int g = 0; g < 16; g += 8)
      #pragma unroll
      for (int i = g; i < g + 4; i++) { t = ((m[i] >> 4) ^ m[i + 4]) & 0x0F0Fu; m[i + 4] ^= t; m[i] ^= t << 4; }
    #pragma unroll
    for (int g = 0; g < 16; g += 4)
      #pragma unroll
      for (int i = g; i < g + 2; i++) { t = ((m[i] >> 2) ^ m[i + 2]) & 0x3333u; m[i + 2] ^= t; m[i] ^= t << 2; }
    #pragma unroll
    for (int g = 0; g < 16; g += 2) { t = ((m[g] >> 1) ^ m[g + 1]) & 0x5555u; m[g + 1] ^= t; m[g] ^= t << 1; }
    #pragma unroll
    for (int r = 0; r < 16; r++) A16[(size_t)(tc * 16 + r) * (NTOT / 16) + tr] = (unsigned short)m[r];
  }
}

// ---------- 2c) repack row-major bits into prop's (rowblk, S4, lane, t) byte order ----------
__global__ __launch_bounds__(256) void repack_kernel(
    const unsigned char* __restrict__ Abits, unsigned int* __restrict__ Apk) {
  int d = blockIdx.x * 256 + threadIdx.x;    // dword index, 2M total
  int lane = d & 63, S4 = (d >> 6) & 63, rowblk = d >> 12;
  int row = rowblk * 16 + (lane & 15), lg = lane >> 4;
  const unsigned int* src = (const unsigned int*)(Abits + (size_t)row * (NTOT / 8) + S4 * 16);
  unsigned int a = src[0], b = src[1], c = src[2], e = src[3];
  int sh = lg * 8;
  Apk[d] = ((a >> sh) & 0xffu) | (((b >> sh) & 0xffu) << 8) |
           (((c >> sh) & 0xffu) << 16) | (((e >> sh) & 0xffu) << 24);
}

// ---------- 3) rdeg = 1/popcount of adjacency rows ----------
__global__ __launch_bounds__(256) void degree_kernel(
    const unsigned long long* __restrict__ A64, float* __restrict__ rdeg) {
  int row = blockIdx.x * 4 + (threadIdx.x >> 6);
  int lane = threadIdx.x & 63;
  const unsigned long long* p = A64 + (size_t)row * (NTOT / 64);
  int cnt = __popcll(p[lane]) + __popcll(p[lane + 64]);
  #pragma unroll
  for (int off = 32; off > 0; off >>= 1) cnt += __shfl_down(cnt, off);
  if (lane == 0) rdeg[row] = (cnt == 0) ? 1.f : 1.f / (float)cnt;
}

// ---------- 4) label init: support one-hot, query zero ----------
__global__ __launch_bounds__(256) void init_labels(
    const int* __restrict__ slab, float* __restrict__ labels,
    unsigned short* __restrict__ Lt) {
  int idx = blockIdx.x * 256 + threadIdx.x;
  int i = idx >> 6, c = idx & 63;
  float v = 0.f;
  if (i < NSUP && slab[i] == c) v = 1.f;
  labels[idx] = v;
  Lt[(size_t)c * NTOT + i] = f2bf(v);
}

// ---------- 5) fused prop iteration: labels' = 0.5*labels + 0.5*(A@L)/deg ----------
// 256 blocks x 512 thr (8 waves): wave (wr 0..1, wk 0..3) = 16 rows x 64 cols x K 2048
__global__ __launch_bounds__(512) void prop_kernel(
    const unsigned int* __restrict__ Apk, const unsigned short* __restrict__ Ltin,
    const float* __restrict__ rdeg, float* __restrict__ labels,
    unsigned short* __restrict__ Ltout, float* __restrict__ outq, int last) {
  __shared__ float red[4][32][65];
  int lane = threadIdx.x & 63;
  int w = threadIdx.x >> 6;
  int wr = w >> 2, wk = w & 3;
  int l15 = lane & 15, lg = lane >> 4;
  int rb = blockIdx.x;
  int rowblk = rb * 2 + wr;
  const unsigned int* ap = Apk + ((size_t)rowblk * 64 + wk * 16) * 64 + lane;
  int kbase = wk * 2048;
  f32x4 acc[4] = {};
  for (int s4 = 0; s4 < 16; s4++) {
    unsigned int d = ap[s4 * 64];
    #pragma unroll
    for (int t = 0; t < 4; t++) {
      unsigned int bb = (d >> (8 * t)) & 0xffu;
      u32x4 uu;
      uu.x = ((bb & 1u)   ? 0x3F80u : 0u) | ((bb & 2u)   ? 0x3F800000u : 0u);
      uu.y = ((bb & 4u)   ? 0x3F80u : 0u) | ((bb & 8u)   ? 0x3F800000u : 0u);
      uu.z = ((bb & 16u)  ? 0x3F80u : 0u) | ((bb & 32u)  ? 0x3F800000u : 0u);
      uu.w = ((bb & 64u)  ? 0x3F80u : 0u) | ((bb & 128u) ? 0x3F800000u : 0u);
      bf16x8 a = __builtin_bit_cast(bf16x8, uu);
      int koff = kbase + (s4 * 4 + t) * 32 + lg * 8;
      #pragma unroll
      for (int fn = 0; fn < 4; fn++) {
        bf16x8 b = *reinterpret_cast<const bf16x8*>(Ltin + (size_t)(fn * 16 + l15) * NTOT + koff);
        acc[fn] = __builtin_amdgcn_mfma_f32_16x16x32_bf16(a, b, acc[fn], 0, 0, 0);
      }
    }
  }
  #pragma unroll
  for (int fn = 0; fn < 4; fn++)
    #pragma unroll
    for (int r = 0; r < 4; r++)
      red[wk][wr * 16 + lg * 4 + r][fn * 16 + l15] = acc[fn][r];
  __syncthreads();
  #pragma unroll
  for (int e = threadIdx.x; e < 32 * 64; e += 512) {
    int il = e >> 6, c = e & 63;
    float s = red[0][il][c] + red[1][il][c] + red[2][il][c] + red[3][il][c];
    int i = rb * 32 + il;
    size_t idx = (size_t)i * NCLS + c;
    float v = 0.5f * labels[idx] + 0.5f * (s * rdeg[i]);
    labels[idx] = v;
    Ltout[(size_t)c * NTOT + i] = f2bf(v);
    if (last && i >= NSUP) outq[idx - (size_t)NSUP * NCLS] = v;
  }
}

extern "C" void kernel_launch(void* const* d_in, const int* in_sizes, int n_in,
                              void* d_out, int out_size, void* d_ws, size_t ws_size,
                              hipStream_t stream) {
  const float* support = (const float*)d_in[0];
  const float* query   = (const float*)d_in[1];
  const float* W       = (const float*)d_in[2];
  const int*   slab    = (const int*)d_in[3];
  float* out = (float*)d_out;
  char* ws = (char*)d_ws;
  const size_t MB = (size_t)1 << 20;
  unsigned char*  Abits  = (unsigned char*)(ws);            // 8 MB  bitpacked adjacency (row-major)
  unsigned int*   Apk    = (unsigned int*)(ws + 8 * MB);    // 8 MB  repacked for prop
  unsigned short* ehi    = (unsigned short*)(ws + 16 * MB); // 4 MB
  unsigned short* elo    = (unsigned short*)(ws + 20 * MB); // 4 MB
  float*          labels = (float*)(ws + 24 * MB);          // 2 MB  fp32 [8192][64]
  unsigned short* Lt0    = (unsigned short*)(ws + 26 * MB); // 1 MB  bf16 [64][8192]
  unsigned short* Lt1    = (unsigned short*)(ws + 27 * MB); // 1 MB
  float*          rdeg   = (float*)(ws + 28 * MB);          // 32 KB

  emb_kernel<<<NTOT / 8, 256, 0, stream>>>(support, query, W, ehi, elo);
  sim_kernel<<<dim3(64, 64), 256, 0, stream>>>(ehi, elo, (unsigned short*)Abits);
  mirror_kernel<<<NTOT / 16, 256, 0, stream>>>((unsigned short*)Abits);
  repack_kernel<<<NTOT * (NTOT / 8) / 4 / 256, 256, 0, stream>>>(Abits, Apk);
  degree_kernel<<<NTOT / 4, 256, 0, stream>>>((const unsigned long long*)Abits, rdeg);
  init_labels<<<NTOT * NCLS / 256, 256, 0, stream>>>(slab, labels, Lt0);
  for (int t = 0; t < 10; t++) {
    unsigned short* Li = (t & 1) ? Lt1 : Lt0;
    unsigned short* Lo = (t & 1) ? Lt0 : Lt1;
    prop_kernel<<<NTOT / 32, 512, 0, stream>>>(Apk, Li, rdeg, labels, Lo, out, (t == 9) ? 1 : 0);
  }
}

// Round 4
// 445.565 us; speedup vs baseline: 2.7658x; 2.1439x over previous
//
#include <hip/hip_runtime.h>

#define NSUP 4096
#define NTOT 8192
#define DIN  512
#define DEMB 256
#define NCLS 64

typedef __attribute__((ext_vector_type(8))) short bf16x8;
typedef __attribute__((ext_vector_type(4))) float f32x4;
typedef __attribute__((ext_vector_type(4))) unsigned int u32x4;

__device__ inline unsigned short f2bf(float x) {
  unsigned int u = __builtin_bit_cast(unsigned int, x);
  u += 0x7FFFu + ((u >> 16) & 1u);   // RNE
  return (unsigned short)(u >> 16);
}
__device__ inline float bf2f(unsigned short h) {
  unsigned int u = ((unsigned int)h) << 16;
  return __builtin_bit_cast(float, u);
}

// fragment-major offset for a [NTOT][DEMB] bf16 matrix:
// eF[row>>4][col>>5][(row&15)+16*((col>>3)&3)][col&7]
__device__ inline size_t efrag(int row, int col) {
  return (((size_t)(row >> 4) * (DEMB / 32) + (col >> 5)) * 64 +
          (row & 15) + 16 * ((col >> 3) & 3)) * 8 + (col & 7);
}
// fragment-major offset for Lt (K=NTOT rows=node i, N=NCLS cols=class c):
// LtF[i>>5][c>>4][(c&15)+16*((i>>3)&3)][i&7]
__device__ inline size_t lfrag(int i, int c) {
  return (((size_t)(i >> 5) * (NCLS / 16) + (c >> 4)) * 64 +
          (c & 15) + 16 * ((i >> 3) & 3)) * 8 + (i & 7);
}

// ---------- 1) emb = [support;query] @ W (fp32) -> bf16 hi/lo, fragment-major ----------
__global__ __launch_bounds__(256) void emb_kernel(
    const float* __restrict__ support, const float* __restrict__ query,
    const float* __restrict__ W, unsigned short* __restrict__ ehiF,
    unsigned short* __restrict__ eloF) {
  int c = threadIdx.x;              // 0..255 = embedding col
  int r0 = blockIdx.x * 8;          // 8 rows per block
  const float* X = (r0 < NSUP) ? (support + (size_t)r0 * DIN)
                               : (query + (size_t)(r0 - NSUP) * DIN);
  float acc[8] = {0.f,0.f,0.f,0.f,0.f,0.f,0.f,0.f};
  #pragma unroll 4
  for (int k = 0; k < DIN; k++) {
    float wv = W[k * DEMB + c];
    #pragma unroll
    for (int r = 0; r < 8; r++) acc[r] += X[r * DIN + k] * wv;
  }
  #pragma unroll
  for (int r = 0; r < 8; r++) {
    float e = acc[r];
    unsigned short h = f2bf(e);
    float lo = e - bf2f(h);
    size_t o = efrag(r0 + r, c);
    ehiF[o] = h;
    eloF[o] = f2bf(lo);
  }
}

// ---------- 2) similarity (split-bf16 MFMA), upper-triangular blocks, frag-major loads ----------
__global__ __launch_bounds__(256) void sim_kernel(
    const unsigned short* __restrict__ ehiF, const unsigned short* __restrict__ eloF,
    unsigned short* __restrict__ Abits) {
  if (blockIdx.x < blockIdx.y) return;     // A symmetric: mirror fills the rest
  int lane = threadIdx.x & 63;
  int w = threadIdx.x >> 6;         // 4 waves, 2x2
  int wm = w >> 1, wn = w & 1;
  int br = blockIdx.y * 128 + wm * 64;
  int bc = blockIdx.x * 128 + wn * 64;
  int l15 = lane & 15, lg = lane >> 4;
  int arb = br >> 4, brb = bc >> 4; // 16-row block indices

  f32x4 acc[4][4] = {};
  for (int kb = 0; kb < DEMB / 32; kb++) {
    bf16x8 bh[4], bl[4];
    #pragma unroll
    for (int fn = 0; fn < 4; fn++) {
      size_t o = (((size_t)(brb + fn) * (DEMB / 32) + kb) * 64 + lane) * 8;
      bh[fn] = *reinterpret_cast<const bf16x8*>(ehiF + o);
      bl[fn] = *reinterpret_cast<const bf16x8*>(eloF + o);
    }
    #pragma unroll
    for (int fm = 0; fm < 4; fm++) {
      size_t o = (((size_t)(arb + fm) * (DEMB / 32) + kb) * 64 + lane) * 8;
      bf16x8 ah = *reinterpret_cast<const bf16x8*>(ehiF + o);
      bf16x8 al = *reinterpret_cast<const bf16x8*>(eloF + o);
      #pragma unroll
      for (int fn = 0; fn < 4; fn++) {
        acc[fm][fn] = __builtin_amdgcn_mfma_f32_16x16x32_bf16(ah, bh[fn], acc[fm][fn], 0, 0, 0);
        acc[fm][fn] = __builtin_amdgcn_mfma_f32_16x16x32_bf16(ah, bl[fn], acc[fm][fn], 0, 0, 0);
        acc[fm][fn] = __builtin_amdgcn_mfma_f32_16x16x32_bf16(al, bh[fn], acc[fm][fn], 0, 0, 0);
      }
    }
  }
  // threshold + ballot-pack: C/D layout col=l&15, row=(l>>4)*4+reg
  #pragma unroll
  for (int fm = 0; fm < 4; fm++) {
    #pragma unroll
    for (int r = 0; r < 4; r++) {
      int grow = br + fm * 16 + lg * 4 + r;
      #pragma unroll
      for (int fn = 0; fn < 4; fn++) {
        unsigned long long bal = __ballot(acc[fm][fn][r] > 0.5f);
        if (l15 == 0) {
          Abits[(size_t)grow * (NTOT / 16) + ((bc + fn * 16) >> 4)] =
              (unsigned short)(bal >> (lg * 16));
        }
      }
    }
  }
}

// ---------- 2b) mirror: fill strictly-lower 16x16 bit-tiles by bit-transpose ----------
__global__ __launch_bounds__(256) void mirror_kernel(unsigned short* __restrict__ A16) {
  int tr = blockIdx.x;                       // source tile row 0..511
  for (int tc = threadIdx.x; tc < NTOT / 16; tc += 256) {
    if ((tc >> 3) <= (tr >> 3)) continue;    // only tiles in strictly-upper 128-blocks
    unsigned int m[16], t;
    #pragma unroll
    for (int r = 0; r < 16; r++) m[r] = A16[(size_t)(tr * 16 + r) * (NTOT / 16) + tc];
    #pragma unroll
    for (int i = 0; i < 8; i++) { t = ((m[i] >> 8) ^ m[i + 8]) & 0x00FFu; m[i + 8] ^= t; m[i] ^= t << 8; }
    #pragma unroll
    for (int g = 0; g < 16; g += 8)
      #pragma unroll
      for (int i = g; i < g + 4; i++) { t = ((m[i] >> 4) ^ m[i + 4]) & 0x0F0Fu; m[i + 4] ^= t; m[i] ^= t << 4; }
    #pragma unroll
    for (int g = 0; g < 16; g += 4)
      #pragma unroll
      for (int i = g; i < g + 2; i++) { t = ((m[i] >> 2) ^ m[i + 2]) & 0x3333u; m[i + 2] ^= t; m[i] ^= t << 2; }
    #pragma unroll
    for (int g = 0; g < 16; g += 2) { t = ((m[g] >> 1) ^ m[g + 1]) & 0x5555u; m[g + 1] ^= t; m[g] ^= t << 1; }
    #pragma unroll
    for (int r = 0; r < 16; r++) A16[(size_t)(tc * 16 + r) * (NTOT / 16) + tr] = (unsigned short)m[r];
  }
}

// ---------- 2c) repack row-major bits into prop's (rowblk, S4, lane, t) byte order ----------
__global__ __launch_bounds__(256) void repack_kernel(
    const unsigned char* __restrict__ Abits, unsigned int* __restrict__ Apk) {
  int d = blockIdx.x * 256 + threadIdx.x;    // dword index, 2M total
  int lane = d & 63, S4 = (d >> 6) & 63, rowblk = d >> 12;
  int row = rowblk * 16 + (lane & 15), lg = lane >> 4;
  const unsigned int* src = (const unsigned int*)(Abits + (size_t)row * (NTOT / 8) + S4 * 16);
  unsigned int a = src[0], b = src[1], c = src[2], e = src[3];
  int sh = lg * 8;
  Apk[d] = ((a >> sh) & 0xffu) | (((b >> sh) & 0xffu) << 8) |
           (((c >> sh) & 0xffu) << 16) | (((e >> sh) & 0xffu) << 24);
}

// ---------- 3) rdeg = 1/popcount of adjacency rows ----------
__global__ __launch_bounds__(256) void degree_kernel(
    const unsigned long long* __restrict__ A64, float* __restrict__ rdeg) {
  int row = blockIdx.x * 4 + (threadIdx.x >> 6);
  int lane = threadIdx.x & 63;
  const unsigned long long* p = A64 + (size_t)row * (NTOT / 64);
  int cnt = __popcll(p[lane]) + __popcll(p[lane + 64]);
  #pragma unroll
  for (int off = 32; off > 0; off >>= 1) cnt += __shfl_down(cnt, off);
  if (lane == 0) rdeg[row] = (cnt == 0) ? 1.f : 1.f / (float)cnt;
}

// ---------- 4) label init: support one-hot, query zero ----------
__global__ __launch_bounds__(256) void init_labels(
    const int* __restrict__ slab, float* __restrict__ labels,
    unsigned short* __restrict__ LtF) {
  int idx = blockIdx.x * 256 + threadIdx.x;
  int i = idx >> 6, c = idx & 63;
  float v = 0.f;
  if (i < NSUP && slab[i] == c) v = 1.f;
  labels[idx] = v;
  LtF[lfrag(i, c)] = f2bf(v);
}

// ---------- 5) fused prop iteration: labels' = 0.5*labels + 0.5*(A@L)/deg ----------
// 512 blocks x 512 thr (8 waves): wave wk owns 16 rows x 64 cols x K-chunk 1024
__global__ __launch_bounds__(512) void prop_kernel(
    const unsigned int* __restrict__ Apk, const unsigned short* __restrict__ LtinF,
    const float* __restrict__ rdeg, float* __restrict__ labels,
    unsigned short* __restrict__ LtoutF, float* __restrict__ outq, int last) {
  __shared__ float red[8][16][67];
  int lane = threadIdx.x & 63;
  int wk = threadIdx.x >> 6;
  int l15 = lane & 15, lg = lane >> 4;
  int rowblk = blockIdx.x;
  const unsigned int* ap = Apk + ((size_t)rowblk * 64 + wk * 8) * 64 + lane;
  int ks0 = wk * 32;                 // kstep base (k = wk*1024)
  f32x4 acc[4] = {};
  for (int s4 = 0; s4 < 8; s4++) {
    unsigned int d = ap[s4 * 64];
    #pragma unroll
    for (int t = 0; t < 4; t++) {
      unsigned int bb = (d >> (8 * t)) & 0xffu;
      u32x4 uu;
      uu.x = ((bb & 1u)   ? 0x3F80u : 0u) | ((bb & 2u)   ? 0x3F800000u : 0u);
      uu.y = ((bb & 4u)   ? 0x3F80u : 0u) | ((bb & 8u)   ? 0x3F800000u : 0u);
      uu.z = ((bb & 16u)  ? 0x3F80u : 0u) | ((bb & 32u)  ? 0x3F800000u : 0u);
      uu.w = ((bb & 64u)  ? 0x3F80u : 0u) | ((bb & 128u) ? 0x3F800000u : 0u);
      bf16x8 a = __builtin_bit_cast(bf16x8, uu);
      int kstep = ks0 + s4 * 4 + t;
      #pragma unroll
      for (int fn = 0; fn < 4; fn++) {
        bf16x8 b = *reinterpret_cast<const bf16x8*>(
            LtinF + (((size_t)kstep * 4 + fn) * 64 + lane) * 8);
        acc[fn] = __builtin_amdgcn_mfma_f32_16x16x32_bf16(a, b, acc[fn], 0, 0, 0);
      }
    }
  }
  #pragma unroll
  for (int fn = 0; fn < 4; fn++)
    #pragma unroll
    for (int r = 0; r < 4; r++)
      red[wk][lg * 4 + r][fn * 16 + l15] = acc[fn][r];
  __syncthreads();
  for (int e = threadIdx.x; e < 16 * 64; e += 512) {
    int il = e >> 6, c = e & 63;
    float s = 0.f;
    #pragma unroll
    for (int p = 0; p < 8; p++) s += red[p][il][c];
    int i = rowblk * 16 + il;
    size_t idx = (size_t)i * NCLS + c;
    float v = 0.5f * labels[idx] + 0.5f * (s * rdeg[i]);
    labels[idx] = v;
    LtoutF[lfrag(i, c)] = f2bf(v);
    if (last && i >= NSUP) outq[idx - (size_t)NSUP * NCLS] = v;
  }
}

extern "C" void kernel_launch(void* const* d_in, const int* in_sizes, int n_in,
                              void* d_out, int out_size, void* d_ws, size_t ws_size,
                              hipStream_t stream) {
  const float* support = (const float*)d_in[0];
  const float* query   = (const float*)d_in[1];
  const float* W       = (const float*)d_in[2];
  const int*   slab    = (const int*)d_in[3];
  float* out = (float*)d_out;
  char* ws = (char*)d_ws;
  const size_t MB = (size_t)1 << 20;
  unsigned char*  Abits  = (unsigned char*)(ws);            // 8 MB  bitpacked adjacency (row-major)
  unsigned int*   Apk    = (unsigned int*)(ws + 8 * MB);    // 8 MB  repacked for prop
  unsigned short* ehiF   = (unsigned short*)(ws + 16 * MB); // 4 MB  fragment-major
  unsigned short* eloF   = (unsigned short*)(ws + 20 * MB); // 4 MB  fragment-major
  float*          labels = (float*)(ws + 24 * MB);          // 2 MB  fp32 [8192][64]
  unsigned short* Lt0    = (unsigned short*)(ws + 26 * MB); // 1 MB  bf16 fragment-major
  unsigned short* Lt1    = (unsigned short*)(ws + 27 * MB); // 1 MB
  float*          rdeg   = (float*)(ws + 28 * MB);          // 32 KB

  emb_kernel<<<NTOT / 8, 256, 0, stream>>>(support, query, W, ehiF, eloF);
  sim_kernel<<<dim3(64, 64), 256, 0, stream>>>(ehiF, eloF, (unsigned short*)Abits);
  mirror_kernel<<<NTOT / 16, 256, 0, stream>>>((unsigned short*)Abits);
  repack_kernel<<<NTOT * (NTOT / 8) / 4 / 256, 256, 0, stream>>>(Abits, Apk);
  degree_kernel<<<NTOT / 4, 256, 0, stream>>>((const unsigned long long*)Abits, rdeg);
  init_labels<<<NTOT * NCLS / 256, 256, 0, stream>>>(slab, labels, Lt0);
  for (int t = 0; t < 10; t++) {
    unsigned short* Li = (t & 1) ? Lt1 : Lt0;
    unsigned short* Lo = (t & 1) ? Lt0 : Lt1;
    prop_kernel<<<NTOT / 16, 512, 0, stream>>>(Apk, Li, rdeg, labels, Lo, out, (t == 9) ? 1 : 0);
  }
}